// Round 1
// baseline (2595.304 us; speedup 1.0000x reference)
//
#include <hip/hip_runtime.h>
#include <math.h>

#define NNODE 100
#define NEGV  -1000000000.0f

// ---------------- static device workspace (ws_size unknown -> avoid d_ws) ---
__device__ float g_Wall [128 * 512];            // [k][c]: Wk^T | Wv^T | G | M^T
__device__ float g_Wall2[128 * 128];            // [k][c]: (Wq@fc1_w)^T
__device__ float g_qcap [128];                  // Wq @ fc_w[:,H]
__device__ float g_C    [(size_t)102400 * 512]; // per (b,n): K|V|K2W|Q1
__device__ float g_qpool[(size_t)1024 * 128];   // per b

// ---------------- kernel 1: fold weights -----------------------------------
__global__ __launch_bounds__(128) void prep_kernel(
    const float* __restrict__ Wk,  const float* __restrict__ Wv,
    const float* __restrict__ Wk2, const float* __restrict__ Wo,
    const float* __restrict__ Wq,  const float* __restrict__ fc_w,
    const float* __restrict__ fc1_w)
{
    const int c = blockIdx.x;
    const int k = threadIdx.x;
    if (c < 128) {                                  // Wk^T
        g_Wall[k * 512 + c] = Wk[c * 128 + k];
    } else if (c < 256) {                           // Wv^T
        g_Wall[k * 512 + c] = Wv[(c - 128) * 128 + k];
    } else if (c < 384) {                           // G = Wk2^T @ Wo
        const int cc = c - 256;
        float acc = 0.f;
        for (int h = 0; h < 128; h++)
            acc = fmaf(Wk2[h * 128 + k], Wo[h * 128 + cc], acc);
        g_Wall[k * 512 + c] = acc;
    } else if (c < 512) {                           // M^T, M = Wq@fc_w[:,:128]
        const int cc = c - 384;
        float acc = 0.f;
        for (int j = 0; j < 128; j++)
            acc = fmaf(Wq[cc * 128 + j], fc_w[j * 129 + k], acc);
        g_Wall[k * 512 + c] = acc;
    } else if (c == 512) {                          // qcap = Wq @ fc_w[:,128]
        float acc = 0.f;
        for (int j = 0; j < 128; j++)
            acc = fmaf(Wq[k * 128 + j], fc_w[j * 129 + 128], acc);
        g_qcap[k] = acc;
    } else {                                        // (Wq@fc1_w)^T
        const int cc = c - 513;
        float acc = 0.f;
        for (int j = 0; j < 128; j++)
            acc = fmaf(Wq[cc * 128 + j], fc1_w[j * 128 + k], acc);
        g_Wall2[k * 128 + cc] = acc;
    }
}

// ---------------- kernel 2: fp32 tiled GEMM  C = A @ W ----------------------
// mode 0: A=enc(102400x128), W=g_Wall(128x512)  -> g_C
// mode 1: A=pool(1024x128),  W=g_Wall2(128x128) -> g_qpool
__global__ __launch_bounds__(256) void gemm_kernel(const float* __restrict__ A,
                                                   int mode)
{
    const float* __restrict__ W = mode ? g_Wall2 : g_Wall;
    float* __restrict__ C       = mode ? g_qpool : g_C;
    const int ncols             = mode ? 128 : 512;
    const int m0 = blockIdx.x * 128, n0 = blockIdx.y * 128;

    __shared__ __align__(16) float At[128 * 132];  // [k][m], pad 132
    __shared__ __align__(16) float Ws[128 * 128];  // [k][n]
    const int tid = threadIdx.x;

    for (int f = tid; f < 4096; f += 256) {
        const int r = f >> 5, q4 = f & 31;
        float4 a = *(const float4*)&A[(size_t)(m0 + r) * 128 + q4 * 4];
        At[(q4 * 4 + 0) * 132 + r] = a.x;
        At[(q4 * 4 + 1) * 132 + r] = a.y;
        At[(q4 * 4 + 2) * 132 + r] = a.z;
        At[(q4 * 4 + 3) * 132 + r] = a.w;
        float4 w = *(const float4*)&W[(size_t)r * ncols + n0 + q4 * 4];
        *(float4*)&Ws[r * 128 + q4 * 4] = w;
    }
    __syncthreads();

    const int tm = tid >> 5, tn = tid & 31;
    const int mb = tm * 16, nb = tn * 4;
    float4 acc[16];
#pragma unroll
    for (int i = 0; i < 16; i++) acc[i] = make_float4(0.f, 0.f, 0.f, 0.f);

    for (int k = 0; k < 128; k++) {
        const float4 w = *(float4*)&Ws[k * 128 + nb];
#pragma unroll
        for (int i = 0; i < 16; i += 4) {
            const float4 a = *(float4*)&At[k * 132 + mb + i];
            acc[i + 0].x = fmaf(a.x, w.x, acc[i + 0].x);
            acc[i + 0].y = fmaf(a.x, w.y, acc[i + 0].y);
            acc[i + 0].z = fmaf(a.x, w.z, acc[i + 0].z);
            acc[i + 0].w = fmaf(a.x, w.w, acc[i + 0].w);
            acc[i + 1].x = fmaf(a.y, w.x, acc[i + 1].x);
            acc[i + 1].y = fmaf(a.y, w.y, acc[i + 1].y);
            acc[i + 1].z = fmaf(a.y, w.z, acc[i + 1].z);
            acc[i + 1].w = fmaf(a.y, w.w, acc[i + 1].w);
            acc[i + 2].x = fmaf(a.z, w.x, acc[i + 2].x);
            acc[i + 2].y = fmaf(a.z, w.y, acc[i + 2].y);
            acc[i + 2].z = fmaf(a.z, w.z, acc[i + 2].z);
            acc[i + 2].w = fmaf(a.z, w.w, acc[i + 2].w);
            acc[i + 3].x = fmaf(a.w, w.x, acc[i + 3].x);
            acc[i + 3].y = fmaf(a.w, w.y, acc[i + 3].y);
            acc[i + 3].z = fmaf(a.w, w.z, acc[i + 3].z);
            acc[i + 3].w = fmaf(a.w, w.w, acc[i + 3].w);
        }
    }
#pragma unroll
    for (int i = 0; i < 16; i++)
        *(float4*)&C[(size_t)(m0 + mb + i) * ncols + n0 + nb] = acc[i];
}

// ---------------- kernel 3: full sequential decode, one block per batch -----
__global__ __launch_bounds__(256) void decode_kernel(
    const float* __restrict__ capacity, const float* __restrict__ demand,
    const int* __restrict__ nsteps_p, const int* __restrict__ T_p,
    float* __restrict__ out)
{
    // swizzled [n][c] storage: float4 chunk c4 of row n lives at ((c4+n)&31)
    __shared__ __align__(16) float Ksh [NNODE * 128];
    __shared__ __align__(16) float Vsh [NNODE * 128];
    __shared__ __align__(16) float K2sh[NNODE * 128];
    __shared__ __align__(16) float attn_t[NNODE * 8];   // [n][h]
    __shared__ __align__(16) float q_sh[128];
    __shared__ __align__(16) float gp_sh[128];
    __shared__ __align__(16) float scratch[1024];       // gpp / u-partial / u
    __shared__ float demand_sh[NNODE];
    __shared__ float mask1_sh[NNODE];
    __shared__ float cap_sh, depot_sh, logp_sh;
    __shared__ int   idx_sh, visited_sh;

    const int tid = threadIdx.x;
    const int b   = blockIdx.x;
    const int nsteps = nsteps_p[0];
    const float Tf = (float)T_p[0];
    const float base_cap = capacity[0];
    const float inv_sqrt_h = 1.0f / sqrtf(128.0f);

    const float* __restrict__ Crow = &g_C[(size_t)b * 100 * 512];

    // stage K|V|K2W (cols 0..383 of each row) into swizzled LDS
    for (int f = tid; f < 100 * 96; f += 256) {
        const int n = f / 96, cc = f % 96;
        const int arr = cc >> 5, c4 = cc & 31;
        float4 v = *(const float4*)&Crow[(size_t)n * 512 + cc * 4];
        float* dst = (arr == 0) ? Ksh : (arr == 1) ? Vsh : K2sh;
        *(float4*)&dst[n * 128 + ((c4 + n) & 31) * 4] = v;
    }
    for (int n = tid; n < 100; n += 256) {
        demand_sh[n] = demand[b * 100 + n];
        mask1_sh[n]  = 0.f;
    }
    if (tid == 0) {
        cap_sh = capacity[b];
        depot_sh = 1.0f;        // mask0: depot masked (go_depot, !all_cust)
        logp_sh = 0.f;
        visited_sh = 0;
        idx_sh = 0;
    }
    float qcapr = 0.f, qpoolr = 0.f, q1row = 0.f;
    if (tid < 128) {
        qcapr  = g_qcap[tid];
        qpoolr = g_qpool[(size_t)b * 128 + tid];
        q1row  = Crow[384 + tid];       // Q1[b,0]  (_inp = enc[:,0,:])
    }
    __syncthreads();

    const int h8 = tid >> 5, l32 = tid & 31;        // scores mapping
    const int c4v = tid & 31, gv = tid >> 5;        // glimpse mapping
    const int nu = tid & 127, half = tid >> 7;      // u mapping

    for (int s = 0; s < nsteps; s++) {
        const float cap = cap_sh;

        // ---- A: q = Q1[prev] + cap*qcap + qpool
        if (tid < 128) q_sh[tid] = q1row + cap * qcapr + qpoolr;
        __syncthreads();

        // ---- B: scores (8 heads x 100) + masked softmax per head
        {
            const float4 qv0 = *(float4*)&q_sh[(h8 * 4 + 0) * 4];
            const float4 qv1 = *(float4*)&q_sh[(h8 * 4 + 1) * 4];
            const float4 qv2 = *(float4*)&q_sh[(h8 * 4 + 2) * 4];
            const float4 qv3 = *(float4*)&q_sh[(h8 * 4 + 3) * 4];
            float sc[4];
#pragma unroll
            for (int j = 0; j < 4; j++) {
                const int n = l32 + 32 * j;
                float sv = NEGV;
                if (n < 100) {
                    const float4 k0 = *(float4*)&Ksh[n * 128 + ((h8 * 4 + 0 + n) & 31) * 4];
                    const float4 k1 = *(float4*)&Ksh[n * 128 + ((h8 * 4 + 1 + n) & 31) * 4];
                    const float4 k2 = *(float4*)&Ksh[n * 128 + ((h8 * 4 + 2 + n) & 31) * 4];
                    const float4 k3 = *(float4*)&Ksh[n * 128 + ((h8 * 4 + 3 + n) & 31) * 4];
                    float d = 0.f;
                    d = fmaf(k0.x, qv0.x, d); d = fmaf(k0.y, qv0.y, d);
                    d = fmaf(k0.z, qv0.z, d); d = fmaf(k0.w, qv0.w, d);
                    d = fmaf(k1.x, qv1.x, d); d = fmaf(k1.y, qv1.y, d);
                    d = fmaf(k1.z, qv1.z, d); d = fmaf(k1.w, qv1.w, d);
                    d = fmaf(k2.x, qv2.x, d); d = fmaf(k2.y, qv2.y, d);
                    d = fmaf(k2.z, qv2.z, d); d = fmaf(k2.w, qv2.w, d);
                    d = fmaf(k3.x, qv3.x, d); d = fmaf(k3.y, qv3.y, d);
                    d = fmaf(k3.z, qv3.z, d); d = fmaf(k3.w, qv3.w, d);
                    const bool m = (n == 0) ? (depot_sh != 0.f)
                        : (mask1_sh[n] != 0.f || demand_sh[n] > cap);
                    sv = m ? NEGV : d * 0.25f;   // 1/sqrt(16) exact
                }
                sc[j] = sv;
            }
            float mx = fmaxf(fmaxf(sc[0], sc[1]), fmaxf(sc[2], sc[3]));
            for (int off = 16; off; off >>= 1)
                mx = fmaxf(mx, __shfl_xor(mx, off, 32));
            float e[4], tot = 0.f;
#pragma unroll
            for (int j = 0; j < 4; j++) { e[j] = expf(sc[j] - mx); tot += e[j]; }
            for (int off = 16; off; off >>= 1) tot += __shfl_xor(tot, off, 32);
#pragma unroll
            for (int j = 0; j < 4; j++) {
                const int n = l32 + 32 * j;
                if (n < 100) attn_t[n * 8 + h8] = e[j] / tot;
            }
        }
        __syncthreads();

        // ---- C: glimpse_pre = attn @ V   (partials over 8 n-groups)
        {
            const int hh = c4v >> 2;
            float4 acc = make_float4(0.f, 0.f, 0.f, 0.f);
            for (int n = gv; n < 100; n += 8) {
                const float a = attn_t[n * 8 + hh];
                const float4 v = *(float4*)&Vsh[n * 128 + ((c4v + n) & 31) * 4];
                acc.x = fmaf(a, v.x, acc.x);
                acc.y = fmaf(a, v.y, acc.y);
                acc.z = fmaf(a, v.z, acc.z);
                acc.w = fmaf(a, v.w, acc.w);
            }
            *(float4*)&scratch[gv * 128 + c4v * 4] = acc;
        }
        __syncthreads();
        if (tid < 128) {
            float ssum = 0.f;
#pragma unroll
            for (int g = 0; g < 8; g++) ssum += scratch[g * 128 + tid];
            gp_sh[tid] = ssum;
        }
        __syncthreads();

        // ---- D: u[n] = 10*tanh( (gp . K2W[n]) / sqrt(128) ), masked, /T
        {
            if (nu < 100) {
                float4 acc = make_float4(0.f, 0.f, 0.f, 0.f);
#pragma unroll
                for (int i = 0; i < 16; i++) {
                    const int c4 = half * 16 + i;
                    const float4 kv = *(float4*)&K2sh[nu * 128 + ((c4 + nu) & 31) * 4];
                    const float4 g4 = *(float4*)&gp_sh[c4 * 4];
                    acc.x = fmaf(kv.x, g4.x, acc.x);
                    acc.y = fmaf(kv.y, g4.y, acc.y);
                    acc.z = fmaf(kv.z, g4.z, acc.z);
                    acc.w = fmaf(kv.w, g4.w, acc.w);
                }
                scratch[half * 128 + nu] = (acc.x + acc.y) + (acc.z + acc.w);
            }
        }
        __syncthreads();
        if (tid < 100) {
            const float z = (scratch[tid] + scratch[128 + tid]) * inv_sqrt_h;
            const float u = 10.0f * tanhf(z);
            const bool m = (tid == 0) ? (depot_sh != 0.f)
                : (mask1_sh[tid] != 0.f || demand_sh[tid] > cap);
            scratch[256 + tid] = (m ? NEGV : u) / Tf;
        }
        __syncthreads();

        // ---- E: argmax + logsumexp + state update (wave 0)
        if (tid < 64) {
            const float v0 = (tid < 100) ? scratch[256 + tid] : -3.0e38f;
            const float v1 = (tid + 64 < 100) ? scratch[256 + tid + 64] : -3.0e38f;
            float bv; int bi;
            if (v1 > v0) { bv = v1; bi = tid + 64; } else { bv = v0; bi = tid; }
            for (int off = 1; off < 64; off <<= 1) {
                const float ov = __shfl_xor(bv, off, 64);
                const int   oi = __shfl_xor(bi, off, 64);
                if (ov > bv || (ov == bv && oi < bi)) { bv = ov; bi = oi; }
            }
            float e0 = (tid < 100) ? expf(v0 - bv) : 0.f;
            float e1 = (tid + 64 < 100) ? expf(v1 - bv) : 0.f;
            float tt = e0 + e1;
            for (int off = 1; off < 64; off <<= 1) tt += __shfl_xor(tt, off, 64);

            const int idx = bi;
            const float capn = (idx == 0) ? base_cap : (cap - demand_sh[idx]);
            // all_cust over n = 1..99 with mask1|new-visit|demand>capn
            const int n1 = tid + 1, n2 = tid + 65;
            const bool m1 = (n1 >= 100) || (mask1_sh[n1] != 0.f) || (n1 == idx)
                            || (demand_sh[n1] > capn);
            const bool m2 = (n2 >= 100) || (mask1_sh[n2] != 0.f) || (n2 == idx)
                            || (demand_sh[n2] > capn);
            const bool allc = __all(m1 && m2);
            if (tid == 0) {
                if (visited_sh < 99) logp_sh += -logf(tt);  // log_p*(1-is_done)
                if (idx > 0) { mask1_sh[idx] = 1.f; visited_sh += 1; }
                cap_sh = capn;
                depot_sh = allc ? 0.f : ((idx == 0) ? 1.f : 0.f);
                idx_sh = idx;
                out[(size_t)b * nsteps + s] = (float)idx;   // actions[b][s]
            }
        }
        __syncthreads();

        // ---- F: prefetch Q1[b, idx] for next step
        if (tid < 128)
            q1row = Crow[(size_t)idx_sh * 512 + 384 + tid];
    }
    if (tid == 0)
        out[(size_t)gridDim.x * nsteps + b] = logp_sh;      // log_p[b]
}

// ---------------- launcher ---------------------------------------------------
extern "C" void kernel_launch(void* const* d_in, const int* in_sizes, int n_in,
                              void* d_out, int out_size, void* d_ws, size_t ws_size,
                              hipStream_t stream) {
    const float* enc    = (const float*)d_in[0];
    const float* pool   = (const float*)d_in[1];
    const float* cap    = (const float*)d_in[2];
    const float* demand = (const float*)d_in[3];
    const float* fc_w   = (const float*)d_in[4];
    const float* fc1_w  = (const float*)d_in[5];
    const float* Wq     = (const float*)d_in[6];
    const float* Wk     = (const float*)d_in[7];
    const float* Wv     = (const float*)d_in[8];
    const float* Wo     = (const float*)d_in[9];
    const float* Wk2    = (const float*)d_in[10];
    const int*   nst    = (const int*)d_in[11];
    const int*   Tp     = (const int*)d_in[12];
    float* out = (float*)d_out;

    prep_kernel<<<641, 128, 0, stream>>>(Wk, Wv, Wk2, Wo, Wq, fc_w, fc1_w);
    gemm_kernel<<<dim3(800, 4), 256, 0, stream>>>(enc, 0);
    gemm_kernel<<<dim3(8, 1),   256, 0, stream>>>(pool, 1);
    decode_kernel<<<1024, 256, 0, stream>>>(cap, demand, nst, Tp, out);
}

// Round 2
// 1639.971 us; speedup vs baseline: 1.5825x; 1.5825x over previous
//
#include <hip/hip_runtime.h>
#include <math.h>

#define NNODE 100
#define NEGV  -1000000000.0f

// ---------------- static device workspace (ws_size unknown -> avoid d_ws) ---
__device__ float g_Wall [128 * 512];            // [k][c]: Wk^T | Wv^T | G | M^T
__device__ float g_Wall2[128 * 128];            // [k][c]: (Wq@fc1_w)^T
__device__ float g_qcap [128];                  // Wq @ fc_w[:,H]
__device__ float g_C    [(size_t)102400 * 512]; // per (b,n): K|V|K2W|Q1
__device__ float g_qpool[(size_t)1024 * 128];   // per b
__device__ float g_S1   [(size_t)1024 * 100 * 800]; // 0.25*((Q1[m]+qpool).K[n,h]) [b][m][h*100+n]
__device__ float g_Scap [(size_t)1024 * 800];       // 0.25*(qcap.K[n,h])          [b][h*100+n]

// ---------------- kernel 1: fold weights -----------------------------------
__global__ __launch_bounds__(128) void prep_kernel(
    const float* __restrict__ Wk,  const float* __restrict__ Wv,
    const float* __restrict__ Wk2, const float* __restrict__ Wo,
    const float* __restrict__ Wq,  const float* __restrict__ fc_w,
    const float* __restrict__ fc1_w)
{
    const int c = blockIdx.x;
    const int k = threadIdx.x;
    if (c < 128) {                                  // Wk^T
        g_Wall[k * 512 + c] = Wk[c * 128 + k];
    } else if (c < 256) {                           // Wv^T
        g_Wall[k * 512 + c] = Wv[(c - 128) * 128 + k];
    } else if (c < 384) {                           // G = Wk2^T @ Wo
        const int cc = c - 256;
        float acc = 0.f;
        for (int h = 0; h < 128; h++)
            acc = fmaf(Wk2[h * 128 + k], Wo[h * 128 + cc], acc);
        g_Wall[k * 512 + c] = acc;
    } else if (c < 512) {                           // M^T, M = Wq@fc_w[:,:128]
        const int cc = c - 384;
        float acc = 0.f;
        for (int j = 0; j < 128; j++)
            acc = fmaf(Wq[cc * 128 + j], fc_w[j * 129 + k], acc);
        g_Wall[k * 512 + c] = acc;
    } else if (c == 512) {                          // qcap = Wq @ fc_w[:,128]
        float acc = 0.f;
        for (int j = 0; j < 128; j++)
            acc = fmaf(Wq[k * 128 + j], fc_w[j * 129 + 128], acc);
        g_qcap[k] = acc;
    } else {                                        // (Wq@fc1_w)^T
        const int cc = c - 513;
        float acc = 0.f;
        for (int j = 0; j < 128; j++)
            acc = fmaf(Wq[cc * 128 + j], fc1_w[j * 128 + k], acc);
        g_Wall2[k * 128 + cc] = acc;
    }
}

// ---------------- kernel 2: fp32 tiled GEMM  C = A @ W ----------------------
__global__ __launch_bounds__(256) void gemm_kernel(const float* __restrict__ A,
                                                   int mode)
{
    const float* __restrict__ W = mode ? g_Wall2 : g_Wall;
    float* __restrict__ C       = mode ? g_qpool : g_C;
    const int ncols             = mode ? 128 : 512;
    const int m0 = blockIdx.x * 128, n0 = blockIdx.y * 128;

    __shared__ __align__(16) float At[128 * 132];
    __shared__ __align__(16) float Ws[128 * 128];
    const int tid = threadIdx.x;

    for (int f = tid; f < 4096; f += 256) {
        const int r = f >> 5, q4 = f & 31;
        float4 a = *(const float4*)&A[(size_t)(m0 + r) * 128 + q4 * 4];
        At[(q4 * 4 + 0) * 132 + r] = a.x;
        At[(q4 * 4 + 1) * 132 + r] = a.y;
        At[(q4 * 4 + 2) * 132 + r] = a.z;
        At[(q4 * 4 + 3) * 132 + r] = a.w;
        float4 w = *(const float4*)&W[(size_t)r * ncols + n0 + q4 * 4];
        *(float4*)&Ws[r * 128 + q4 * 4] = w;
    }
    __syncthreads();

    const int tm = tid >> 5, tn = tid & 31;
    const int mb = tm * 16, nb = tn * 4;
    float4 acc[16];
#pragma unroll
    for (int i = 0; i < 16; i++) acc[i] = make_float4(0.f, 0.f, 0.f, 0.f);

    for (int k = 0; k < 128; k++) {
        const float4 w = *(float4*)&Ws[k * 128 + nb];
#pragma unroll
        for (int i = 0; i < 16; i += 4) {
            const float4 a = *(float4*)&At[k * 132 + mb + i];
            acc[i + 0].x = fmaf(a.x, w.x, acc[i + 0].x);
            acc[i + 0].y = fmaf(a.x, w.y, acc[i + 0].y);
            acc[i + 0].z = fmaf(a.x, w.z, acc[i + 0].z);
            acc[i + 0].w = fmaf(a.x, w.w, acc[i + 0].w);
            acc[i + 1].x = fmaf(a.y, w.x, acc[i + 1].x);
            acc[i + 1].y = fmaf(a.y, w.y, acc[i + 1].y);
            acc[i + 1].z = fmaf(a.y, w.z, acc[i + 1].z);
            acc[i + 1].w = fmaf(a.y, w.w, acc[i + 1].w);
            acc[i + 2].x = fmaf(a.z, w.x, acc[i + 2].x);
            acc[i + 2].y = fmaf(a.z, w.y, acc[i + 2].y);
            acc[i + 2].z = fmaf(a.z, w.z, acc[i + 2].z);
            acc[i + 2].w = fmaf(a.z, w.w, acc[i + 2].w);
            acc[i + 3].x = fmaf(a.w, w.x, acc[i + 3].x);
            acc[i + 3].y = fmaf(a.w, w.y, acc[i + 3].y);
            acc[i + 3].z = fmaf(a.w, w.z, acc[i + 3].z);
            acc[i + 3].w = fmaf(a.w, w.w, acc[i + 3].w);
        }
    }
#pragma unroll
    for (int i = 0; i < 16; i++)
        *(float4*)&C[(size_t)(m0 + mb + i) * ncols + n0 + nb] = acc[i];
}

// ---------------- kernel 2.5: per-batch score fold --------------------------
// S1[b][m][h*100+n] = 0.25*((Q1[b,m]+ ... ) . K[b,n,h])   with qpool folded in
// Scap[b][h*100+n]  = 0.25*(qcap . K[b,n,h])
__global__ __launch_bounds__(256) void s1_kernel()
{
    const int b = blockIdx.x;
    const int tid = threadIdx.x;
    const int h = tid >> 5, l32 = tid & 31;
    const float* __restrict__ Crow = &g_C[(size_t)b * 100 * 512];

    __shared__ __align__(16) float Q1sh[NNODE * 128];
    for (int f = tid; f < 3200; f += 256) {
        const int n = f >> 5, c4 = f & 31;
        *(float4*)&Q1sh[n * 128 + c4 * 4] =
            *(const float4*)&Crow[(size_t)n * 512 + 384 + c4 * 4];
    }
    __syncthreads();

    // K fragments for this thread's 4 nodes (head h, cols h*16..h*16+15)
    float4 kr[4][4];
    int nn[4];
#pragma unroll
    for (int j = 0; j < 4; j++) {
        nn[j] = l32 + 32 * j;
#pragma unroll
        for (int i = 0; i < 4; i++) {
            kr[j][i] = (nn[j] < 100)
                ? *(const float4*)&Crow[(size_t)nn[j] * 512 + h * 16 + i * 4]
                : make_float4(0.f, 0.f, 0.f, 0.f);
        }
    }
    float4 qc[4], qp[4];
#pragma unroll
    for (int i = 0; i < 4; i++) {
        qc[i] = *(const float4*)&g_qcap[h * 16 + i * 4];
        qp[i] = *(const float4*)&g_qpool[(size_t)b * 128 + h * 16 + i * 4];
    }
    float sp[4];
#pragma unroll
    for (int j = 0; j < 4; j++) {
        float dc = 0.f, dp = 0.f;
#pragma unroll
        for (int i = 0; i < 4; i++) {
            dc = fmaf(kr[j][i].x, qc[i].x, dc); dc = fmaf(kr[j][i].y, qc[i].y, dc);
            dc = fmaf(kr[j][i].z, qc[i].z, dc); dc = fmaf(kr[j][i].w, qc[i].w, dc);
            dp = fmaf(kr[j][i].x, qp[i].x, dp); dp = fmaf(kr[j][i].y, qp[i].y, dp);
            dp = fmaf(kr[j][i].z, qp[i].z, dp); dp = fmaf(kr[j][i].w, qp[i].w, dp);
        }
        sp[j] = dp;
        if (nn[j] < 100)
            g_Scap[(size_t)b * 800 + h * 100 + nn[j]] = dc * 0.25f;
    }

    float* __restrict__ S1b = &g_S1[(size_t)b * 80000];
    for (int m = 0; m < 100; m++) {
        float4 q[4];
#pragma unroll
        for (int i = 0; i < 4; i++)
            q[i] = *(float4*)&Q1sh[m * 128 + h * 16 + i * 4];
#pragma unroll
        for (int j = 0; j < 4; j++) {
            if (nn[j] < 100) {
                float d = 0.f;
#pragma unroll
                for (int i = 0; i < 4; i++) {
                    d = fmaf(kr[j][i].x, q[i].x, d); d = fmaf(kr[j][i].y, q[i].y, d);
                    d = fmaf(kr[j][i].z, q[i].z, d); d = fmaf(kr[j][i].w, q[i].w, d);
                }
                S1b[(size_t)m * 800 + h * 100 + nn[j]] = (d + sp[j]) * 0.25f;
            }
        }
    }
}

// ---------------- kernel 3: full sequential decode, one block per batch -----
__global__ __launch_bounds__(256, 2) void decode_kernel(
    const float* __restrict__ capacity, const float* __restrict__ demand,
    const int* __restrict__ nsteps_p, const int* __restrict__ T_p,
    float* __restrict__ out)
{
    __shared__ __align__(16) float Vsh [NNODE * 128];   // swizzled [n][chunk]
    __shared__ __align__(16) float S1sh[800];           // current prev-row
    __shared__ __align__(16) float Scap_sh[800];
    __shared__ __align__(16) float attn_t[800];         // [h][n]
    __shared__ __align__(16) float gp_sh[128];
    __shared__ __align__(16) float scratch[1024];
    __shared__ float demand_sh[NNODE];
    __shared__ float mask1_sh[NNODE];
    __shared__ float cap_sh, depot_sh, logp_sh;
    __shared__ int   idx_sh, visited_sh;

    const int tid = threadIdx.x;
    const int b   = blockIdx.x;
    const int nsteps = nsteps_p[0];
    const float Tf = (float)T_p[0];
    const float base_cap = capacity[0];
    const float inv_sqrt_h = 1.0f / sqrtf(128.0f);

    const float* __restrict__ Crow = &g_C[(size_t)b * 100 * 512];
    const float* __restrict__ S1b  = &g_S1[(size_t)b * 80000];

    // stage V (cols 128..255) into swizzled LDS
    for (int f = tid; f < 3200; f += 256) {
        const int n = f >> 5, c4 = f & 31;
        float4 v = *(const float4*)&Crow[(size_t)n * 512 + 128 + c4 * 4];
        *(float4*)&Vsh[n * 128 + ((c4 + n) & 31) * 4] = v;
    }
    if (tid < 200) {
        *(float4*)&Scap_sh[tid * 4] = *(const float4*)&g_Scap[(size_t)b * 800 + tid * 4];
        *(float4*)&S1sh[tid * 4]    = *(const float4*)&S1b[tid * 4];   // prev=0 row
    }
    for (int n = tid; n < 100; n += 256) {
        demand_sh[n] = demand[b * 100 + n];
        mask1_sh[n]  = 0.f;
    }
    if (tid == 0) {
        cap_sh = capacity[b];
        depot_sh = 1.0f;
        logp_sh = 0.f;
        visited_sh = 0;
        idx_sh = 0;
    }
    // K2W fragments in registers: node n = tid&127, cols half*64..half*64+63
    const int nD = tid & 127, half = tid >> 7;
    float4 k2r[16];
#pragma unroll
    for (int i = 0; i < 16; i++)
        k2r[i] = (nD < 100)
            ? *(const float4*)&Crow[(size_t)nD * 512 + 256 + (half * 16 + i) * 4]
            : make_float4(0.f, 0.f, 0.f, 0.f);
    __syncthreads();

    const int h8 = tid >> 5, l32 = tid & 31;        // scores mapping
    const int c4v = tid & 31, gv = tid >> 5;        // glimpse mapping
    const int hh = c4v >> 2;

    for (int s = 0; s < nsteps; s++) {
        const float cap = cap_sh;

        // ---- B: scores = S1 + cap*Scap (masked) + per-head softmax
        {
            float sc[4];
#pragma unroll
            for (int j = 0; j < 4; j++) {
                const int n = l32 + 32 * j;
                float sv = NEGV;
                if (n < 100) {
                    const int a = h8 * 100 + n;
                    const float raw = fmaf(cap, Scap_sh[a], S1sh[a]);
                    const bool m = (n == 0) ? (depot_sh != 0.f)
                        : (mask1_sh[n] != 0.f || demand_sh[n] > cap);
                    sv = m ? NEGV : raw;
                }
                sc[j] = sv;
            }
            float mx = fmaxf(fmaxf(sc[0], sc[1]), fmaxf(sc[2], sc[3]));
            for (int off = 16; off; off >>= 1)
                mx = fmaxf(mx, __shfl_xor(mx, off, 32));
            float e[4], tot = 0.f;
#pragma unroll
            for (int j = 0; j < 4; j++) { e[j] = expf(sc[j] - mx); tot += e[j]; }
            for (int off = 16; off; off >>= 1) tot += __shfl_xor(tot, off, 32);
            const float r = 1.f / tot;
#pragma unroll
            for (int j = 0; j < 4; j++) {
                const int n = l32 + 32 * j;
                if (n < 100) attn_t[h8 * 100 + n] = e[j] * r;
            }
        }
        __syncthreads();

        // ---- C: glimpse partials  (attn @ V)
        {
            float4 acc = make_float4(0.f, 0.f, 0.f, 0.f);
            for (int n = gv; n < 100; n += 8) {
                const float a = attn_t[hh * 100 + n];
                const float4 v = *(float4*)&Vsh[n * 128 + ((c4v + n) & 31) * 4];
                acc.x = fmaf(a, v.x, acc.x);
                acc.y = fmaf(a, v.y, acc.y);
                acc.z = fmaf(a, v.z, acc.z);
                acc.w = fmaf(a, v.w, acc.w);
            }
            *(float4*)&scratch[gv * 128 + c4v * 4] = acc;
        }
        __syncthreads();

        // ---- C2: reduce 8 partials -> gp
        if (tid < 128) {
            float ssum = 0.f;
#pragma unroll
            for (int g = 0; g < 8; g++) ssum += scratch[g * 128 + tid];
            gp_sh[tid] = ssum;
        }
        __syncthreads();

        // ---- D: u partials = gp . K2W[n]  (K2W in registers, gp broadcast)
        if (nD < 100) {
            float4 acc = make_float4(0.f, 0.f, 0.f, 0.f);
#pragma unroll
            for (int i = 0; i < 16; i++) {
                const float4 kv = k2r[i];
                const float4 g4 = *(float4*)&gp_sh[(half * 16 + i) * 4];
                acc.x = fmaf(kv.x, g4.x, acc.x);
                acc.y = fmaf(kv.y, g4.y, acc.y);
                acc.z = fmaf(kv.z, g4.z, acc.z);
                acc.w = fmaf(kv.w, g4.w, acc.w);
            }
            scratch[half * 128 + nD] = (acc.x + acc.y) + (acc.z + acc.w);
        }
        __syncthreads();

        // ---- E: tanh + mask + argmax + logsumexp + state update (wave 0)
        if (tid < 64) {
            float v0, v1 = -3.0e38f;
            {
                const float z = (scratch[tid] + scratch[128 + tid]) * inv_sqrt_h;
                const float u = 10.0f * tanhf(z);
                const bool m = (tid == 0) ? (depot_sh != 0.f)
                    : (mask1_sh[tid] != 0.f || demand_sh[tid] > cap);
                v0 = (m ? NEGV : u) / Tf;
            }
            if (tid + 64 < 100) {
                const int n1 = tid + 64;
                const float z = (scratch[n1] + scratch[128 + n1]) * inv_sqrt_h;
                const float u = 10.0f * tanhf(z);
                const bool m = (mask1_sh[n1] != 0.f || demand_sh[n1] > cap);
                v1 = (m ? NEGV : u) / Tf;
            }
            float bv; int bi;
            if (v1 > v0) { bv = v1; bi = tid + 64; } else { bv = v0; bi = tid; }
            for (int off = 1; off < 64; off <<= 1) {
                const float ov = __shfl_xor(bv, off, 64);
                const int   oi = __shfl_xor(bi, off, 64);
                if (ov > bv || (ov == bv && oi < bi)) { bv = ov; bi = oi; }
            }
            float e0 = expf(v0 - bv);
            float e1 = (tid + 64 < 100) ? expf(v1 - bv) : 0.f;
            float tt = e0 + e1;
            for (int off = 1; off < 64; off <<= 1) tt += __shfl_xor(tt, off, 64);

            const int idx = bi;
            const float capn = (idx == 0) ? base_cap : (cap - demand_sh[idx]);
            const int n1 = tid + 1, n2 = tid + 65;
            const bool m1 = (n1 >= 100) || (mask1_sh[n1] != 0.f) || (n1 == idx)
                            || (demand_sh[n1] > capn);
            const bool m2 = (n2 >= 100) || (mask1_sh[n2] != 0.f) || (n2 == idx)
                            || (demand_sh[n2] > capn);
            const bool allc = __all(m1 && m2);
            if (tid == 0) {
                if (visited_sh < 99) logp_sh += -logf(tt);
                if (idx > 0) { mask1_sh[idx] = 1.f; visited_sh += 1; }
                cap_sh = capn;
                depot_sh = allc ? 0.f : ((idx == 0) ? 1.f : 0.f);
                idx_sh = idx;
                out[(size_t)b * nsteps + s] = (float)idx;
            }
        }
        __syncthreads();

        // ---- F: fetch S1 row of new prev into LDS
        if (tid < 200)
            *(float4*)&S1sh[tid * 4] =
                *(const float4*)&S1b[(size_t)idx_sh * 800 + tid * 4];
        __syncthreads();
    }
    if (tid == 0)
        out[(size_t)gridDim.x * nsteps + b] = logp_sh;
}

// ---------------- launcher ---------------------------------------------------
extern "C" void kernel_launch(void* const* d_in, const int* in_sizes, int n_in,
                              void* d_out, int out_size, void* d_ws, size_t ws_size,
                              hipStream_t stream) {
    const float* enc    = (const float*)d_in[0];
    const float* pool   = (const float*)d_in[1];
    const float* cap    = (const float*)d_in[2];
    const float* demand = (const float*)d_in[3];
    const float* fc_w   = (const float*)d_in[4];
    const float* fc1_w  = (const float*)d_in[5];
    const float* Wq     = (const float*)d_in[6];
    const float* Wk     = (const float*)d_in[7];
    const float* Wv     = (const float*)d_in[8];
    const float* Wo     = (const float*)d_in[9];
    const float* Wk2    = (const float*)d_in[10];
    const int*   nst    = (const int*)d_in[11];
    const int*   Tp     = (const int*)d_in[12];
    float* out = (float*)d_out;

    prep_kernel<<<641, 128, 0, stream>>>(Wk, Wv, Wk2, Wo, Wq, fc_w, fc1_w);
    gemm_kernel<<<dim3(800, 4), 256, 0, stream>>>(enc, 0);
    gemm_kernel<<<dim3(8, 1),   256, 0, stream>>>(pool, 1);
    s1_kernel<<<1024, 256, 0, stream>>>();
    decode_kernel<<<1024, 256, 0, stream>>>(cap, demand, nst, Tp, out);
}

// Round 3
// 1305.637 us; speedup vs baseline: 1.9878x; 1.2561x over previous
//
#include <hip/hip_runtime.h>
#include <math.h>

#define NNODE 100
#define NEGV  -1000000000.0f

// ---------------- static device workspace (ws_size unknown -> avoid d_ws) ---
__device__ float g_Wall [128 * 512];            // [k][c]: Wk^T | Wv^T | G | M^T
__device__ float g_Wall2[128 * 128];            // [k][c]: (Wq@fc1_w)^T
__device__ float g_qcap [128];                  // Wq @ fc_w[:,H]
__device__ float g_C    [(size_t)102400 * 512]; // per (b,n): K|V|K2W|Q1
__device__ float g_qpool[(size_t)1024 * 128];   // per b
__device__ float g_S1   [(size_t)1024 * 100 * 800]; // [b][m][h*100+n]
__device__ float g_Scap [(size_t)1024 * 800];       // [b][h*100+n]

// ---------------- kernel 1: fold weights -----------------------------------
__global__ __launch_bounds__(128) void prep_kernel(
    const float* __restrict__ Wk,  const float* __restrict__ Wv,
    const float* __restrict__ Wk2, const float* __restrict__ Wo,
    const float* __restrict__ Wq,  const float* __restrict__ fc_w,
    const float* __restrict__ fc1_w)
{
    const int c = blockIdx.x;
    const int k = threadIdx.x;
    if (c < 128) {
        g_Wall[k * 512 + c] = Wk[c * 128 + k];
    } else if (c < 256) {
        g_Wall[k * 512 + c] = Wv[(c - 128) * 128 + k];
    } else if (c < 384) {                           // G = Wk2^T @ Wo
        const int cc = c - 256;
        float acc = 0.f;
        for (int h = 0; h < 128; h++)
            acc = fmaf(Wk2[h * 128 + k], Wo[h * 128 + cc], acc);
        g_Wall[k * 512 + c] = acc;
    } else if (c < 512) {                           // M^T, M = Wq@fc_w[:,:128]
        const int cc = c - 384;
        float acc = 0.f;
        for (int j = 0; j < 128; j++)
            acc = fmaf(Wq[cc * 128 + j], fc_w[j * 129 + k], acc);
        g_Wall[k * 512 + c] = acc;
    } else if (c == 512) {                          // qcap = Wq @ fc_w[:,128]
        float acc = 0.f;
        for (int j = 0; j < 128; j++)
            acc = fmaf(Wq[k * 128 + j], fc_w[j * 129 + 128], acc);
        g_qcap[k] = acc;
    } else {                                        // (Wq@fc1_w)^T
        const int cc = c - 513;
        float acc = 0.f;
        for (int j = 0; j < 128; j++)
            acc = fmaf(Wq[cc * 128 + j], fc1_w[j * 128 + k], acc);
        g_Wall2[k * 128 + cc] = acc;
    }
}

// ---------------- kernel 2: fp32 tiled GEMM, k-chunked (33 KB LDS, 4/CU) ----
__global__ __launch_bounds__(256) void gemm_kernel(const float* __restrict__ A,
                                                   int mode)
{
    const float* __restrict__ W = mode ? g_Wall2 : g_Wall;
    float* __restrict__ C       = mode ? g_qpool : g_C;
    const int ncols             = mode ? 128 : 512;
    const int m0 = blockIdx.x * 128, n0 = blockIdx.y * 128;

    __shared__ __align__(16) float At[32 * 132];   // [k_local][m]
    __shared__ __align__(16) float Ws[32 * 128];   // [k_local][n]
    const int tid = threadIdx.x;
    const int tm = tid >> 5, tn = tid & 31;
    const int mb = tm * 16, nb = tn * 4;
    float4 acc[16];
#pragma unroll
    for (int i = 0; i < 16; i++) acc[i] = make_float4(0.f, 0.f, 0.f, 0.f);

    for (int kc = 0; kc < 4; kc++) {
        for (int f = tid; f < 1024; f += 256) {
            const int r = f >> 3, q8 = f & 7;      // A: m-row r, k-f4 q8
            float4 a = *(const float4*)&A[(size_t)(m0 + r) * 128 + kc * 32 + q8 * 4];
            At[(q8 * 4 + 0) * 132 + r] = a.x;
            At[(q8 * 4 + 1) * 132 + r] = a.y;
            At[(q8 * 4 + 2) * 132 + r] = a.z;
            At[(q8 * 4 + 3) * 132 + r] = a.w;
            const int kl = f >> 5, q = f & 31;     // W: k-row kl, n-f4 q
            *(float4*)&Ws[kl * 128 + q * 4] =
                *(const float4*)&W[(size_t)(kc * 32 + kl) * ncols + n0 + q * 4];
        }
        __syncthreads();
        for (int k = 0; k < 32; k++) {
            const float4 w = *(float4*)&Ws[k * 128 + nb];
#pragma unroll
            for (int i = 0; i < 16; i += 4) {
                const float4 a = *(float4*)&At[k * 132 + mb + i];
                acc[i + 0].x = fmaf(a.x, w.x, acc[i + 0].x);
                acc[i + 0].y = fmaf(a.x, w.y, acc[i + 0].y);
                acc[i + 0].z = fmaf(a.x, w.z, acc[i + 0].z);
                acc[i + 0].w = fmaf(a.x, w.w, acc[i + 0].w);
                acc[i + 1].x = fmaf(a.y, w.x, acc[i + 1].x);
                acc[i + 1].y = fmaf(a.y, w.y, acc[i + 1].y);
                acc[i + 1].z = fmaf(a.y, w.z, acc[i + 1].z);
                acc[i + 1].w = fmaf(a.y, w.w, acc[i + 1].w);
                acc[i + 2].x = fmaf(a.z, w.x, acc[i + 2].x);
                acc[i + 2].y = fmaf(a.z, w.y, acc[i + 2].y);
                acc[i + 2].z = fmaf(a.z, w.z, acc[i + 2].z);
                acc[i + 2].w = fmaf(a.z, w.w, acc[i + 2].w);
                acc[i + 3].x = fmaf(a.w, w.x, acc[i + 3].x);
                acc[i + 3].y = fmaf(a.w, w.y, acc[i + 3].y);
                acc[i + 3].z = fmaf(a.w, w.z, acc[i + 3].z);
                acc[i + 3].w = fmaf(a.w, w.w, acc[i + 3].w);
            }
        }
        __syncthreads();
    }
#pragma unroll
    for (int i = 0; i < 16; i++)
        *(float4*)&C[(size_t)(m0 + mb + i) * ncols + n0 + nb] = acc[i];
}

// ---------------- kernel 2.5: per-batch score fold --------------------------
__global__ __launch_bounds__(256) void s1_kernel()
{
    const int b = blockIdx.x;
    const int tid = threadIdx.x;
    const int h = tid >> 5, l32 = tid & 31;
    const float* __restrict__ Crow = &g_C[(size_t)b * 100 * 512];

    __shared__ __align__(16) float Q1sh[NNODE * 128];
    for (int f = tid; f < 3200; f += 256) {
        const int n = f >> 5, c4 = f & 31;
        *(float4*)&Q1sh[n * 128 + c4 * 4] =
            *(const float4*)&Crow[(size_t)n * 512 + 384 + c4 * 4];
    }
    __syncthreads();

    float4 kr[4][4];
    int nn[4];
#pragma unroll
    for (int j = 0; j < 4; j++) {
        nn[j] = l32 + 32 * j;
#pragma unroll
        for (int i = 0; i < 4; i++) {
            kr[j][i] = (nn[j] < 100)
                ? *(const float4*)&Crow[(size_t)nn[j] * 512 + h * 16 + i * 4]
                : make_float4(0.f, 0.f, 0.f, 0.f);
        }
    }
    float4 qc[4], qp[4];
#pragma unroll
    for (int i = 0; i < 4; i++) {
        qc[i] = *(const float4*)&g_qcap[h * 16 + i * 4];
        qp[i] = *(const float4*)&g_qpool[(size_t)b * 128 + h * 16 + i * 4];
    }
    float sp[4];
#pragma unroll
    for (int j = 0; j < 4; j++) {
        float dc = 0.f, dp = 0.f;
#pragma unroll
        for (int i = 0; i < 4; i++) {
            dc = fmaf(kr[j][i].x, qc[i].x, dc); dc = fmaf(kr[j][i].y, qc[i].y, dc);
            dc = fmaf(kr[j][i].z, qc[i].z, dc); dc = fmaf(kr[j][i].w, qc[i].w, dc);
            dp = fmaf(kr[j][i].x, qp[i].x, dp); dp = fmaf(kr[j][i].y, qp[i].y, dp);
            dp = fmaf(kr[j][i].z, qp[i].z, dp); dp = fmaf(kr[j][i].w, qp[i].w, dp);
        }
        sp[j] = dp;
        if (nn[j] < 100)
            g_Scap[(size_t)b * 800 + h * 100 + nn[j]] = dc * 0.25f;
    }

    float* __restrict__ S1b = &g_S1[(size_t)b * 80000];
    for (int m = 0; m < 100; m++) {
        float4 q[4];
#pragma unroll
        for (int i = 0; i < 4; i++)
            q[i] = *(float4*)&Q1sh[m * 128 + h * 16 + i * 4];
#pragma unroll
        for (int j = 0; j < 4; j++) {
            if (nn[j] < 100) {
                float d = 0.f;
#pragma unroll
                for (int i = 0; i < 4; i++) {
                    d = fmaf(kr[j][i].x, q[i].x, d); d = fmaf(kr[j][i].y, q[i].y, d);
                    d = fmaf(kr[j][i].z, q[i].z, d); d = fmaf(kr[j][i].w, q[i].w, d);
                }
                S1b[(size_t)m * 800 + h * 100 + nn[j]] = (d + sp[j]) * 0.25f;
            }
        }
    }
}

// ---------------- kernel 3: sequential decode, V/K2W in registers -----------
__global__ __launch_bounds__(256, 2) void decode_kernel(
    const float* __restrict__ capacity, const float* __restrict__ demand,
    const int* __restrict__ nsteps_p, const int* __restrict__ T_p,
    float* __restrict__ out)
{
    __shared__ __align__(16) float attn_sh[800];   // [h][n], unnormalized e
    __shared__ __align__(16) float part[512];      // [wave][c]; gp in part[0:128]
    __shared__ float rtot_sh[8];
    __shared__ float u_sh[NNODE];
    __shared__ float demand_sh[NNODE];
    __shared__ float mask1_sh[NNODE];
    __shared__ float cap_sh, depot_sh, logp_sh;
    __shared__ int   idx_sh, visited_sh;

    const int tid = threadIdx.x;
    const int b   = blockIdx.x;
    const int nsteps = nsteps_p[0];
    const float invT = 1.0f / (float)T_p[0];
    const float base_cap = capacity[0];
    const float inv_sqrt_h = 1.0f / sqrtf(128.0f);

    const float4* __restrict__ C4 = (const float4*)&g_C[(size_t)b * 100 * 512];
    const float*  __restrict__ S1b = &g_S1[(size_t)b * 80000];

    // ---- mappings
    const int w = tid >> 6, sub = (tid >> 5) & 1, q = tid & 31;  // glimpse
    const int res = (sub << 2) | w;                 // node residue mod 8
    const int NV = (res < 4) ? 13 : 12;
    const int h8 = tid >> 5, l32 = tid & 31;        // scores
    const int nD = tid >> 1, half = tid & 1;        // u phase (tid<200)

    // ---- persistent registers
    float4 Vreg[13];                                // V[res+8m][q*4..]
#pragma unroll
    for (int m = 0; m < 13; m++) {
        Vreg[m] = (m < NV) ? C4[(size_t)(res + 8 * m) * 128 + 32 + q]
                           : make_float4(0.f, 0.f, 0.f, 0.f);
    }
    float4 k2r[16];                                 // K2W[nD][half*64 + ...]
#pragma unroll
    for (int i = 0; i < 16; i++)
        k2r[i] = (tid < 200) ? C4[(size_t)nD * 128 + 64 + half * 16 + i]
                             : make_float4(0.f, 0.f, 0.f, 0.f);
    float scapr[4], s1r[4], d4[4];
#pragma unroll
    for (int j = 0; j < 4; j++) {
        const int nj = l32 + 32 * j;
        const bool v = nj < 100;
        scapr[j] = v ? g_Scap[(size_t)b * 800 + h8 * 100 + nj] : 0.f;
        s1r[j]   = v ? S1b[h8 * 100 + nj] : 0.f;    // prev = 0 row
        d4[j]    = v ? demand[b * 100 + nj] : 1.0e30f;
    }

    for (int n = tid; n < 100; n += 256) {
        demand_sh[n] = demand[b * 100 + n];
        mask1_sh[n]  = 0.f;
    }
    if (tid == 0) {
        cap_sh = capacity[b];
        depot_sh = 1.0f;
        logp_sh = 0.f;
        visited_sh = 0;
        idx_sh = 0;
    }
    __syncthreads();

    for (int s = 0; s < nsteps; s++) {
        const float cap = cap_sh;

        // ---- B: scores + per-head softmax (e written unnormalized)
        {
            float sc[4];
#pragma unroll
            for (int j = 0; j < 4; j++) {
                const int nj = l32 + 32 * j;
                float sv = NEGV;
                if (nj < 100) {
                    const float raw = fmaf(cap, scapr[j], s1r[j]);
                    const bool m = (nj == 0) ? (depot_sh != 0.f)
                        : (mask1_sh[nj] != 0.f || d4[j] > cap);
                    sv = m ? NEGV : raw;
                }
                sc[j] = sv;
            }
            float mx = fmaxf(fmaxf(sc[0], sc[1]), fmaxf(sc[2], sc[3]));
            for (int off = 16; off; off >>= 1)
                mx = fmaxf(mx, __shfl_xor(mx, off, 32));
            float tot = 0.f;
#pragma unroll
            for (int j = 0; j < 4; j++) {
                const int nj = l32 + 32 * j;
                const float e = expf(sc[j] - mx);
                if (nj < 100) attn_sh[h8 * 100 + nj] = e;
                tot += e;
            }
            for (int off = 16; off; off >>= 1) tot += __shfl_xor(tot, off, 32);
            if (l32 == 0) rtot_sh[h8] = 1.0f / tot;
        }
        __syncthreads();

        // ---- C: glimpse from register-resident V + shfl combine
        {
            float4 acc = make_float4(0.f, 0.f, 0.f, 0.f);
            const int hq = q >> 2;
#pragma unroll
            for (int m = 0; m < 13; m++) {
                float a = 0.f;
                if (m < NV) a = attn_sh[hq * 100 + res + 8 * m];
                acc.x = fmaf(a, Vreg[m].x, acc.x);
                acc.y = fmaf(a, Vreg[m].y, acc.y);
                acc.z = fmaf(a, Vreg[m].z, acc.z);
                acc.w = fmaf(a, Vreg[m].w, acc.w);
            }
            const float rt = rtot_sh[hq];
            acc.x *= rt; acc.y *= rt; acc.z *= rt; acc.w *= rt;
            acc.x += __shfl_xor(acc.x, 32, 64);
            acc.y += __shfl_xor(acc.y, 32, 64);
            acc.z += __shfl_xor(acc.z, 32, 64);
            acc.w += __shfl_xor(acc.w, 32, 64);
            if (sub == 0) *(float4*)&part[w * 128 + q * 4] = acc;
        }
        __syncthreads();

        // ---- C2: combine 4 wave partials -> gp (in part[0:128])
        if (tid < 128) {
            const float sgp = part[tid] + part[128 + tid]
                            + part[256 + tid] + part[384 + tid];
            part[tid] = sgp;
        }
        __syncthreads();

        // ---- D: u = 10*tanh(gp.K2W / sqrt128), masked, *invT
        if (tid < 200) {
            float4 a = make_float4(0.f, 0.f, 0.f, 0.f);
#pragma unroll
            for (int i = 0; i < 16; i++) {
                const float4 g4 = *(float4*)&part[(half * 16 + i) * 4];
                a.x = fmaf(k2r[i].x, g4.x, a.x);
                a.y = fmaf(k2r[i].y, g4.y, a.y);
                a.z = fmaf(k2r[i].z, g4.z, a.z);
                a.w = fmaf(k2r[i].w, g4.w, a.w);
            }
            float up = (a.x + a.y) + (a.z + a.w);
            up += __shfl_xor(up, 1, 64);
            if (half == 0) {
                const float u = 10.0f * tanhf(up * inv_sqrt_h);
                const bool m = (nD == 0) ? (depot_sh != 0.f)
                    : (mask1_sh[nD] != 0.f || demand_sh[nD] > cap);
                u_sh[nD] = (m ? NEGV : u) * invT;
            }
        }
        __syncthreads();

        // ---- E: argmax + logsumexp + state update (wave 0)
        if (tid < 64) {
            const float v0 = u_sh[tid];
            const float v1 = (tid + 64 < 100) ? u_sh[tid + 64] : -3.0e38f;
            float bv; int bi;
            if (v1 > v0) { bv = v1; bi = tid + 64; } else { bv = v0; bi = tid; }
            for (int off = 1; off < 64; off <<= 1) {
                const float ov = __shfl_xor(bv, off, 64);
                const int   oi = __shfl_xor(bi, off, 64);
                if (ov > bv || (ov == bv && oi < bi)) { bv = ov; bi = oi; }
            }
            float tt = expf(v0 - bv)
                     + ((tid + 64 < 100) ? expf(v1 - bv) : 0.f);
            for (int off = 1; off < 64; off <<= 1) tt += __shfl_xor(tt, off, 64);

            const int idx = bi;
            const float capn = (idx == 0) ? base_cap : (cap - demand_sh[idx]);
            const int n1 = tid + 1, n2 = tid + 65;
            const bool m1 = (n1 >= 100) || (mask1_sh[n1] != 0.f) || (n1 == idx)
                            || (demand_sh[n1] > capn);
            const bool m2 = (n2 >= 100) || (mask1_sh[n2] != 0.f) || (n2 == idx)
                            || (demand_sh[n2] > capn);
            const bool allc = __all(m1 && m2);
            if (tid == 0) {
                if (visited_sh < 99) logp_sh += -logf(tt);
                if (idx > 0) { mask1_sh[idx] = 1.f; visited_sh += 1; }
                cap_sh = capn;
                depot_sh = allc ? 0.f : ((idx == 0) ? 1.f : 0.f);
                idx_sh = idx;
                out[(size_t)b * nsteps + s] = (float)idx;
            }
        }
        __syncthreads();

        // ---- F: prefetch next S1 row into registers (no barrier needed)
        {
            const int pidx = idx_sh;
#pragma unroll
            for (int j = 0; j < 4; j++) {
                const int nj = l32 + 32 * j;
                if (nj < 100)
                    s1r[j] = S1b[(size_t)pidx * 800 + h8 * 100 + nj];
            }
        }
    }
    if (tid == 0)
        out[(size_t)gridDim.x * nsteps + b] = logp_sh;
}

// ---------------- launcher ---------------------------------------------------
extern "C" void kernel_launch(void* const* d_in, const int* in_sizes, int n_in,
                              void* d_out, int out_size, void* d_ws, size_t ws_size,
                              hipStream_t stream) {
    const float* enc    = (const float*)d_in[0];
    const float* pool   = (const float*)d_in[1];
    const float* cap    = (const float*)d_in[2];
    const float* demand = (const float*)d_in[3];
    const float* fc_w   = (const float*)d_in[4];
    const float* fc1_w  = (const float*)d_in[5];
    const float* Wq     = (const float*)d_in[6];
    const float* Wk     = (const float*)d_in[7];
    const float* Wv     = (const float*)d_in[8];
    const float* Wo     = (const float*)d_in[9];
    const float* Wk2    = (const float*)d_in[10];
    const int*   nst    = (const int*)d_in[11];
    const int*   Tp     = (const int*)d_in[12];
    float* out = (float*)d_out;

    prep_kernel<<<641, 128, 0, stream>>>(Wk, Wv, Wk2, Wo, Wq, fc_w, fc1_w);
    gemm_kernel<<<dim3(800, 4), 256, 0, stream>>>(enc, 0);
    gemm_kernel<<<dim3(8, 1),   256, 0, stream>>>(pool, 1);
    s1_kernel<<<1024, 256, 0, stream>>>();
    decode_kernel<<<1024, 256, 0, stream>>>(cap, demand, nst, Tp, out);
}

// Round 4
// 1214.137 us; speedup vs baseline: 2.1376x; 1.0754x over previous
//
#include <hip/hip_runtime.h>
#include <math.h>

#define NNODE 100
#define NEGV  -1000000000.0f

// ---------------- static device workspace (ws_size unknown -> avoid d_ws) ---
__device__ float g_Wall [128 * 512];            // [k][c]: Wk^T | Wv^T | G | M^T
__device__ float g_Wall2[128 * 128];            // [k][c]: (Wq@fc1_w)^T
__device__ float g_qcap [128];                  // Wq @ fc_w[:,H]
__device__ float g_C    [(size_t)102400 * 512]; // per (b,n): K|V|K2W|Q1
__device__ float g_qpool[(size_t)1024 * 128];   // per b
__device__ float g_S1   [(size_t)1024 * 100 * 800]; // [b][m][h*100+n]
__device__ float g_Scap [(size_t)1024 * 800];       // [b][h*100+n]

// ---------------- kernel 1: fold weights -----------------------------------
__global__ __launch_bounds__(128) void prep_kernel(
    const float* __restrict__ Wk,  const float* __restrict__ Wv,
    const float* __restrict__ Wk2, const float* __restrict__ Wo,
    const float* __restrict__ Wq,  const float* __restrict__ fc_w,
    const float* __restrict__ fc1_w)
{
    const int c = blockIdx.x;
    const int k = threadIdx.x;
    if (c < 128) {
        g_Wall[k * 512 + c] = Wk[c * 128 + k];
    } else if (c < 256) {
        g_Wall[k * 512 + c] = Wv[(c - 128) * 128 + k];
    } else if (c < 384) {                           // G = Wk2^T @ Wo
        const int cc = c - 256;
        float acc = 0.f;
        for (int h = 0; h < 128; h++)
            acc = fmaf(Wk2[h * 128 + k], Wo[h * 128 + cc], acc);
        g_Wall[k * 512 + c] = acc;
    } else if (c < 512) {                           // M^T, M = Wq@fc_w[:,:128]
        const int cc = c - 384;
        float acc = 0.f;
        for (int j = 0; j < 128; j++)
            acc = fmaf(Wq[cc * 128 + j], fc_w[j * 129 + k], acc);
        g_Wall[k * 512 + c] = acc;
    } else if (c == 512) {                          // qcap = Wq @ fc_w[:,128]
        float acc = 0.f;
        for (int j = 0; j < 128; j++)
            acc = fmaf(Wq[k * 128 + j], fc_w[j * 129 + 128], acc);
        g_qcap[k] = acc;
    } else {                                        // (Wq@fc1_w)^T
        const int cc = c - 513;
        float acc = 0.f;
        for (int j = 0; j < 128; j++)
            acc = fmaf(Wq[cc * 128 + j], fc1_w[j * 128 + k], acc);
        g_Wall2[k * 128 + cc] = acc;
    }
}

// ---------------- kernel 2: fp32 tiled GEMM, k-chunked (33 KB LDS) ----------
__global__ __launch_bounds__(256) void gemm_kernel(const float* __restrict__ A,
                                                   int mode)
{
    const float* __restrict__ W = mode ? g_Wall2 : g_Wall;
    float* __restrict__ C       = mode ? g_qpool : g_C;
    const int ncols             = mode ? 128 : 512;
    const int m0 = blockIdx.x * 128, n0 = blockIdx.y * 128;

    __shared__ __align__(16) float At[32 * 132];   // [k_local][m]
    __shared__ __align__(16) float Ws[32 * 128];   // [k_local][n]
    const int tid = threadIdx.x;
    const int tm = tid >> 5, tn = tid & 31;
    const int mb = tm * 16, nb = tn * 4;
    float4 acc[16];
#pragma unroll
    for (int i = 0; i < 16; i++) acc[i] = make_float4(0.f, 0.f, 0.f, 0.f);

    for (int kc = 0; kc < 4; kc++) {
        for (int f = tid; f < 1024; f += 256) {
            const int r = f >> 3, q8 = f & 7;
            float4 a = *(const float4*)&A[(size_t)(m0 + r) * 128 + kc * 32 + q8 * 4];
            At[(q8 * 4 + 0) * 132 + r] = a.x;
            At[(q8 * 4 + 1) * 132 + r] = a.y;
            At[(q8 * 4 + 2) * 132 + r] = a.z;
            At[(q8 * 4 + 3) * 132 + r] = a.w;
            const int kl = f >> 5, q = f & 31;
            *(float4*)&Ws[kl * 128 + q * 4] =
                *(const float4*)&W[(size_t)(kc * 32 + kl) * ncols + n0 + q * 4];
        }
        __syncthreads();
        for (int k = 0; k < 32; k++) {
            const float4 w = *(float4*)&Ws[k * 128 + nb];
#pragma unroll
            for (int i = 0; i < 16; i += 4) {
                const float4 a = *(float4*)&At[k * 132 + mb + i];
                acc[i + 0].x = fmaf(a.x, w.x, acc[i + 0].x);
                acc[i + 0].y = fmaf(a.x, w.y, acc[i + 0].y);
                acc[i + 0].z = fmaf(a.x, w.z, acc[i + 0].z);
                acc[i + 0].w = fmaf(a.x, w.w, acc[i + 0].w);
                acc[i + 1].x = fmaf(a.y, w.x, acc[i + 1].x);
                acc[i + 1].y = fmaf(a.y, w.y, acc[i + 1].y);
                acc[i + 1].z = fmaf(a.y, w.z, acc[i + 1].z);
                acc[i + 1].w = fmaf(a.y, w.w, acc[i + 1].w);
                acc[i + 2].x = fmaf(a.z, w.x, acc[i + 2].x);
                acc[i + 2].y = fmaf(a.z, w.y, acc[i + 2].y);
                acc[i + 2].z = fmaf(a.z, w.z, acc[i + 2].z);
                acc[i + 2].w = fmaf(a.z, w.w, acc[i + 2].w);
                acc[i + 3].x = fmaf(a.w, w.x, acc[i + 3].x);
                acc[i + 3].y = fmaf(a.w, w.y, acc[i + 3].y);
                acc[i + 3].z = fmaf(a.w, w.z, acc[i + 3].z);
                acc[i + 3].w = fmaf(a.w, w.w, acc[i + 3].w);
            }
        }
        __syncthreads();
    }
#pragma unroll
    for (int i = 0; i < 16; i++)
        *(float4*)&C[(size_t)(m0 + mb + i) * ncols + n0 + nb] = acc[i];
}

// ---------------- kernel 2.5: per-batch score fold --------------------------
__global__ __launch_bounds__(256) void s1_kernel()
{
    const int b = blockIdx.x;
    const int tid = threadIdx.x;
    const int h = tid >> 5, l32 = tid & 31;
    const float* __restrict__ Crow = &g_C[(size_t)b * 100 * 512];

    __shared__ __align__(16) float Q1sh[NNODE * 128];
    for (int f = tid; f < 3200; f += 256) {
        const int n = f >> 5, c4 = f & 31;
        *(float4*)&Q1sh[n * 128 + c4 * 4] =
            *(const float4*)&Crow[(size_t)n * 512 + 384 + c4 * 4];
    }
    __syncthreads();

    float4 kr[4][4];
    int nn[4];
#pragma unroll
    for (int j = 0; j < 4; j++) {
        nn[j] = l32 + 32 * j;
#pragma unroll
        for (int i = 0; i < 4; i++) {
            kr[j][i] = (nn[j] < 100)
                ? *(const float4*)&Crow[(size_t)nn[j] * 512 + h * 16 + i * 4]
                : make_float4(0.f, 0.f, 0.f, 0.f);
        }
    }
    float4 qc[4], qp[4];
#pragma unroll
    for (int i = 0; i < 4; i++) {
        qc[i] = *(const float4*)&g_qcap[h * 16 + i * 4];
        qp[i] = *(const float4*)&g_qpool[(size_t)b * 128 + h * 16 + i * 4];
    }
    float sp[4];
#pragma unroll
    for (int j = 0; j < 4; j++) {
        float dc = 0.f, dp = 0.f;
#pragma unroll
        for (int i = 0; i < 4; i++) {
            dc = fmaf(kr[j][i].x, qc[i].x, dc); dc = fmaf(kr[j][i].y, qc[i].y, dc);
            dc = fmaf(kr[j][i].z, qc[i].z, dc); dc = fmaf(kr[j][i].w, qc[i].w, dc);
            dp = fmaf(kr[j][i].x, qp[i].x, dp); dp = fmaf(kr[j][i].y, qp[i].y, dp);
            dp = fmaf(kr[j][i].z, qp[i].z, dp); dp = fmaf(kr[j][i].w, qp[i].w, dp);
        }
        sp[j] = dp;
        if (nn[j] < 100)
            g_Scap[(size_t)b * 800 + h * 100 + nn[j]] = dc * 0.25f;
    }

    float* __restrict__ S1b = &g_S1[(size_t)b * 80000];
    for (int m = 0; m < 100; m++) {
        float4 q[4];
#pragma unroll
        for (int i = 0; i < 4; i++)
            q[i] = *(float4*)&Q1sh[m * 128 + h * 16 + i * 4];
#pragma unroll
        for (int j = 0; j < 4; j++) {
            if (nn[j] < 100) {
                float d = 0.f;
#pragma unroll
                for (int i = 0; i < 4; i++) {
                    d = fmaf(kr[j][i].x, q[i].x, d); d = fmaf(kr[j][i].y, q[i].y, d);
                    d = fmaf(kr[j][i].z, q[i].z, d); d = fmaf(kr[j][i].w, q[i].w, d);
                }
                S1b[(size_t)m * 800 + h * 100 + nn[j]] = (d + sp[j]) * 0.25f;
            }
        }
    }
}

// ---------------- kernel 3: sequential decode, 1 barrier/step ----------------
// wave w owns heads 2w,2w+1 and gp cols 32w..32w+31. lane l: g=l>>3 (node
// residue mod 8), f=l&7 (float4-col within wave). All state in registers;
// only u-partials cross waves (double-buffered LDS).
__global__ __launch_bounds__(256) void decode_kernel(
    const float* __restrict__ capacity, const float* __restrict__ demand,
    const int* __restrict__ nsteps_p, const int* __restrict__ T_p,
    float* __restrict__ out)
{
    __shared__ float u_buf[2 * 800];    // [parity][r<8][n<100]
    __shared__ int   act_sh[512];

    const int tid = threadIdx.x;
    const int b   = blockIdx.x;
    const int nsteps = nsteps_p[0];
    const float invT = 1.0f / (float)T_p[0];
    const float base_cap = capacity[0];
    const float inv_sqrt_h = 0.08838834764831845f;  // 1/sqrt(128)

    const float4* __restrict__ C4  = (const float4*)&g_C[(size_t)b * 100 * 512];
    const float*  __restrict__ S1b = &g_S1[(size_t)b * 80000];

    const int w = tid >> 6, l = tid & 63;
    const int g = l >> 3, f = l & 7;
    const int F = 8 * w + f;                 // global float4 col 0..31
    const int h8 = tid >> 5, l32 = tid & 31; // B mapping: head h8, nodes l32+32j

    // ---- persistent registers
    float4 Vreg[13], K2r[13];
#pragma unroll
    for (int m = 0; m < 13; m++) {
        const int n = g + 8 * m;
        const bool v = n < 100;
        Vreg[m] = v ? C4[(size_t)n * 128 + 32 + F] : make_float4(0.f, 0.f, 0.f, 0.f);
        K2r[m]  = v ? C4[(size_t)n * 128 + 64 + F] : make_float4(0.f, 0.f, 0.f, 0.f);
    }
    float s1r[4], scapr[4], d4[4];
#pragma unroll
    for (int j = 0; j < 4; j++) {
        const int nj = l32 + 32 * j;
        const bool v = nj < 100;
        scapr[j] = v ? g_Scap[(size_t)b * 800 + h8 * 100 + nj] : 0.f;
        s1r[j]   = v ? S1b[h8 * 100 + nj] : 0.f;
        d4[j]    = v ? demand[b * 100 + nj] : 1.0e30f;
    }
    const float de0 = demand[b * 100 + l];
    const float de1 = (l + 64 < 100) ? demand[b * 100 + l + 64] : 1.0e30f;
    bool me0 = false, me1 = false;      // mask1 for nodes l, l+64
    unsigned mb4 = 0;                   // mask1 bits for B's 4 nodes
    float cap_r = capacity[b];
    float depot_r;
    {
        const bool am0 = (l == 0) ? true : (de0 > cap_r);
        const bool am1 = (l + 64 >= 100) ? true : (de1 > cap_r);
        depot_r = __all(am0 && am1) ? 0.f : 1.f;
    }
    float logp_r = 0.f;
    int visited_r = 0;
    int ub = 0;

    for (int s = 0; s < nsteps; s++) {
        const float cap = cap_r;

        // ---- B: scores + per-head softmax, normalized attn in a[]
        float a[4];
        {
            float sc[4];
#pragma unroll
            for (int j = 0; j < 4; j++) {
                const int nj = l32 + 32 * j;
                const bool m = (nj == 0) ? (depot_r != 0.f)
                    : (((mb4 >> j) & 1u) || (d4[j] > cap));
                const float raw = fmaf(cap, scapr[j], s1r[j]);
                sc[j] = (nj < 100 && !m) ? raw : NEGV;
            }
            float mx = fmaxf(fmaxf(sc[0], sc[1]), fmaxf(sc[2], sc[3]));
            for (int off = 16; off; off >>= 1)
                mx = fmaxf(mx, __shfl_xor(mx, off, 32));
            float tot = 0.f;
#pragma unroll
            for (int j = 0; j < 4; j++) { a[j] = expf(sc[j] - mx); tot += a[j]; }
            for (int off = 16; off; off >>= 1) tot += __shfl_xor(tot, off, 32);
            const float rt = 1.0f / tot;
#pragma unroll
            for (int j = 0; j < 4; j++) a[j] *= rt;
        }

        // ---- C: glimpse cols 4F..4F+3 (attn via intra-wave shfl)
        float4 gp4 = make_float4(0.f, 0.f, 0.f, 0.f);
#pragma unroll
        for (int m = 0; m < 13; m++) {
            const int src = ((f >> 2) << 5) | (8 * (m & 3) + g);
            const float av = __shfl(a[m >> 2], src, 64);
            gp4.x = fmaf(av, Vreg[m].x, gp4.x);
            gp4.y = fmaf(av, Vreg[m].y, gp4.y);
            gp4.z = fmaf(av, Vreg[m].z, gp4.z);
            gp4.w = fmaf(av, Vreg[m].w, gp4.w);
        }
#pragma unroll
        for (int off = 8; off <= 32; off <<= 1) {
            gp4.x += __shfl_xor(gp4.x, off, 64);
            gp4.y += __shfl_xor(gp4.y, off, 64);
            gp4.z += __shfl_xor(gp4.z, off, 64);
            gp4.w += __shfl_xor(gp4.w, off, 64);
        }

        // ---- U: u-partials over this wave's 32 cols -> u_buf rows 2w,2w+1
        {
            float pm[13];
#pragma unroll
            for (int m = 0; m < 13; m++) {
                float p = gp4.x * K2r[m].x;
                p = fmaf(gp4.y, K2r[m].y, p);
                p = fmaf(gp4.z, K2r[m].z, p);
                p = fmaf(gp4.w, K2r[m].w, p);
                pm[m] = p;
            }
#pragma unroll
            for (int m = 0; m < 13; m++) pm[m] += __shfl_xor(pm[m], 1, 64);
#pragma unroll
            for (int m = 0; m < 13; m++) pm[m] += __shfl_xor(pm[m], 2, 64);
            if ((f & 3) == 0) {
                const int r = w * 2 + (f >> 2);
#pragma unroll
                for (int m = 0; m < 13; m++) {
                    const int n = g + 8 * m;
                    if (n < 100) u_buf[ub + r * 100 + n] = pm[m];
                }
            }
        }
        __syncthreads();

        // ---- E: redundant per-wave argmax + lse + state update
        float v0, v1 = -3.0e38f;
        {
            float s8 = 0.f;
#pragma unroll
            for (int r = 0; r < 8; r++) s8 += u_buf[ub + r * 100 + l];
            const float u0 = 10.0f * tanhf(s8 * inv_sqrt_h);
            const bool m0 = (l == 0) ? (depot_r != 0.f) : (me0 || de0 > cap);
            v0 = (m0 ? NEGV : u0) * invT;
            if (l + 64 < 100) {
                float t8 = 0.f;
#pragma unroll
                for (int r = 0; r < 8; r++) t8 += u_buf[ub + r * 100 + l + 64];
                const float u1 = 10.0f * tanhf(t8 * inv_sqrt_h);
                const bool m1 = (me1 || de1 > cap);
                v1 = (m1 ? NEGV : u1) * invT;
            }
        }
        float bv; int bi;
        if (v1 > v0) { bv = v1; bi = l + 64; } else { bv = v0; bi = l; }
#pragma unroll
        for (int off = 1; off < 64; off <<= 1) {
            const float ov = __shfl_xor(bv, off, 64);
            const int   oi = __shfl_xor(bi, off, 64);
            if (ov > bv || (ov == bv && oi < bi)) { bv = ov; bi = oi; }
        }
        const int idx = bi;

        // prefetch next S1 row ASAP (overlaps rest of E)
#pragma unroll
        for (int j = 0; j < 4; j++) {
            const int nj = l32 + 32 * j;
            if (nj < 100)
                s1r[j] = S1b[(size_t)idx * 800 + h8 * 100 + nj];
        }

        float tt = expf(v0 - bv) + ((l + 64 < 100) ? expf(v1 - bv) : 0.f);
#pragma unroll
        for (int off = 1; off < 64; off <<= 1) tt += __shfl_xor(tt, off, 64);

        const float d_sel = (idx >= 64) ? de1 : de0;
        const float dmd_idx = __shfl(d_sel, idx & 63, 64);
        const float capn = (idx == 0) ? base_cap : (cap - dmd_idx);

        if (visited_r < 99) logp_r += -logf(tt);
        visited_r += (idx > 0) ? 1 : 0;
        me0 = me0 || (l == idx && idx > 0);
        me1 = me1 || (l + 64 == idx);
#pragma unroll
        for (int j = 0; j < 4; j++)
            if ((l32 + 32 * j) == idx && idx > 0) mb4 |= (1u << j);

        const bool am0 = (l == 0) ? true : (me0 || de0 > capn);
        const bool am1 = (l + 64 >= 100) ? true : (me1 || de1 > capn);
        const bool allc = __all(am0 && am1);
        depot_r = allc ? 0.f : ((idx == 0) ? 1.f : 0.f);
        cap_r = capn;
        if (tid == 0) act_sh[s] = idx;
        ub ^= 800;
    }

    __syncthreads();
    for (int t = tid; t < nsteps; t += 256)
        out[(size_t)b * nsteps + t] = (float)act_sh[t];
    if (tid == 0)
        out[(size_t)gridDim.x * nsteps + b] = logp_r;
}

// ---------------- launcher ---------------------------------------------------
extern "C" void kernel_launch(void* const* d_in, const int* in_sizes, int n_in,
                              void* d_out, int out_size, void* d_ws, size_t ws_size,
                              hipStream_t stream) {
    const float* enc    = (const float*)d_in[0];
    const float* pool   = (const float*)d_in[1];
    const float* cap    = (const float*)d_in[2];
    const float* demand = (const float*)d_in[3];
    const float* fc_w   = (const float*)d_in[4];
    const float* fc1_w  = (const float*)d_in[5];
    const float* Wq     = (const float*)d_in[6];
    const float* Wk     = (const float*)d_in[7];
    const float* Wv     = (const float*)d_in[8];
    const float* Wo     = (const float*)d_in[9];
    const float* Wk2    = (const float*)d_in[10];
    const int*   nst    = (const int*)d_in[11];
    const int*   Tp     = (const int*)d_in[12];
    float* out = (float*)d_out;

    prep_kernel<<<641, 128, 0, stream>>>(Wk, Wv, Wk2, Wo, Wq, fc_w, fc1_w);
    gemm_kernel<<<dim3(800, 4), 256, 0, stream>>>(enc, 0);
    gemm_kernel<<<dim3(8, 1),   256, 0, stream>>>(pool, 1);
    s1_kernel<<<1024, 256, 0, stream>>>();
    decode_kernel<<<1024, 256, 0, stream>>>(cap, demand, nst, Tp, out);
}

// Round 5
// 1156.506 us; speedup vs baseline: 2.2441x; 1.0498x over previous
//
#include <hip/hip_runtime.h>
#include <math.h>

#define NNODE 100
#define NEGV  -1000000000.0f

// ---------------- static device workspace (ws_size unknown -> avoid d_ws) ---
__device__ float g_Wall [128 * 512];            // [k][c]: Wk^T | Wv^T | G | M^T
__device__ float g_Wall2[128 * 128];            // [k][c]: (Wq@fc1_w)^T
__device__ float g_qcap [128];                  // Wq @ fc_w[:,H]
__device__ float g_C    [(size_t)102400 * 512]; // per (b,n): K|V|K2W|Q1
__device__ float g_qpool[(size_t)1024 * 128];   // per b
__device__ float g_S1   [(size_t)1024 * 100 * 800]; // [b][m][h*100+n]
__device__ float g_Scap [(size_t)1024 * 800];       // [b][h*100+n]

// fast transcendentals: ~1e-7 rel err, well below the ~1e-5 fold noise the
// pipeline already tolerates at absmax 0.0
__device__ __forceinline__ float fast_exp(float x)  { return __expf(x); }
__device__ __forceinline__ float fast_rcp(float x)  { return __builtin_amdgcn_rcpf(x); }
__device__ __forceinline__ float tanh10(float z) {
    // 10*tanh(z) = 10 - 20/(exp(2z)+1); exp->inf => 10, exp->0 => -10 (safe)
    const float e2 = __expf(2.0f * z);
    return fmaf(-20.0f, __builtin_amdgcn_rcpf(e2 + 1.0f), 10.0f);
}

// ---------------- kernel 1: fold weights -----------------------------------
__global__ __launch_bounds__(128) void prep_kernel(
    const float* __restrict__ Wk,  const float* __restrict__ Wv,
    const float* __restrict__ Wk2, const float* __restrict__ Wo,
    const float* __restrict__ Wq,  const float* __restrict__ fc_w,
    const float* __restrict__ fc1_w)
{
    const int c = blockIdx.x;
    const int k = threadIdx.x;
    if (c < 128) {
        g_Wall[k * 512 + c] = Wk[c * 128 + k];
    } else if (c < 256) {
        g_Wall[k * 512 + c] = Wv[(c - 128) * 128 + k];
    } else if (c < 384) {                           // G = Wk2^T @ Wo
        const int cc = c - 256;
        float acc = 0.f;
        for (int h = 0; h < 128; h++)
            acc = fmaf(Wk2[h * 128 + k], Wo[h * 128 + cc], acc);
        g_Wall[k * 512 + c] = acc;
    } else if (c < 512) {                           // M^T, M = Wq@fc_w[:,:128]
        const int cc = c - 384;
        float acc = 0.f;
        for (int j = 0; j < 128; j++)
            acc = fmaf(Wq[cc * 128 + j], fc_w[j * 129 + k], acc);
        g_Wall[k * 512 + c] = acc;
    } else if (c == 512) {                          // qcap = Wq @ fc_w[:,128]
        float acc = 0.f;
        for (int j = 0; j < 128; j++)
            acc = fmaf(Wq[k * 128 + j], fc_w[j * 129 + 128], acc);
        g_qcap[k] = acc;
    } else {                                        // (Wq@fc1_w)^T
        const int cc = c - 513;
        float acc = 0.f;
        for (int j = 0; j < 128; j++)
            acc = fmaf(Wq[cc * 128 + j], fc1_w[j * 128 + k], acc);
        g_Wall2[k * 128 + cc] = acc;
    }
}

// ---------------- kernel 2: fp32 tiled GEMM, k-chunked (33 KB LDS) ----------
__global__ __launch_bounds__(256) void gemm_kernel(const float* __restrict__ A,
                                                   int mode)
{
    const float* __restrict__ W = mode ? g_Wall2 : g_Wall;
    float* __restrict__ C       = mode ? g_qpool : g_C;
    const int ncols             = mode ? 128 : 512;
    const int m0 = blockIdx.x * 128, n0 = blockIdx.y * 128;

    __shared__ __align__(16) float At[32 * 132];   // [k_local][m]
    __shared__ __align__(16) float Ws[32 * 128];   // [k_local][n]
    const int tid = threadIdx.x;
    const int tm = tid >> 5, tn = tid & 31;
    const int mb = tm * 16, nb = tn * 4;
    float4 acc[16];
#pragma unroll
    for (int i = 0; i < 16; i++) acc[i] = make_float4(0.f, 0.f, 0.f, 0.f);

    for (int kc = 0; kc < 4; kc++) {
        for (int f = tid; f < 1024; f += 256) {
            const int r = f >> 3, q8 = f & 7;
            float4 a = *(const float4*)&A[(size_t)(m0 + r) * 128 + kc * 32 + q8 * 4];
            At[(q8 * 4 + 0) * 132 + r] = a.x;
            At[(q8 * 4 + 1) * 132 + r] = a.y;
            At[(q8 * 4 + 2) * 132 + r] = a.z;
            At[(q8 * 4 + 3) * 132 + r] = a.w;
            const int kl = f >> 5, q = f & 31;
            *(float4*)&Ws[kl * 128 + q * 4] =
                *(const float4*)&W[(size_t)(kc * 32 + kl) * ncols + n0 + q * 4];
        }
        __syncthreads();
        for (int k = 0; k < 32; k++) {
            const float4 w = *(float4*)&Ws[k * 128 + nb];
#pragma unroll
            for (int i = 0; i < 16; i += 4) {
                const float4 a = *(float4*)&At[k * 132 + mb + i];
                acc[i + 0].x = fmaf(a.x, w.x, acc[i + 0].x);
                acc[i + 0].y = fmaf(a.x, w.y, acc[i + 0].y);
                acc[i + 0].z = fmaf(a.x, w.z, acc[i + 0].z);
                acc[i + 0].w = fmaf(a.x, w.w, acc[i + 0].w);
                acc[i + 1].x = fmaf(a.y, w.x, acc[i + 1].x);
                acc[i + 1].y = fmaf(a.y, w.y, acc[i + 1].y);
                acc[i + 1].z = fmaf(a.y, w.z, acc[i + 1].z);
                acc[i + 1].w = fmaf(a.y, w.w, acc[i + 1].w);
                acc[i + 2].x = fmaf(a.z, w.x, acc[i + 2].x);
                acc[i + 2].y = fmaf(a.z, w.y, acc[i + 2].y);
                acc[i + 2].z = fmaf(a.z, w.z, acc[i + 2].z);
                acc[i + 2].w = fmaf(a.z, w.w, acc[i + 2].w);
                acc[i + 3].x = fmaf(a.w, w.x, acc[i + 3].x);
                acc[i + 3].y = fmaf(a.w, w.y, acc[i + 3].y);
                acc[i + 3].z = fmaf(a.w, w.z, acc[i + 3].z);
                acc[i + 3].w = fmaf(a.w, w.w, acc[i + 3].w);
            }
        }
        __syncthreads();
    }
#pragma unroll
    for (int i = 0; i < 16; i++)
        *(float4*)&C[(size_t)(m0 + mb + i) * ncols + n0 + nb] = acc[i];
}

// ---------------- kernel 2.5: per-batch score fold --------------------------
__global__ __launch_bounds__(256) void s1_kernel()
{
    const int b = blockIdx.x;
    const int tid = threadIdx.x;
    const int h = tid >> 5, l32 = tid & 31;
    const float* __restrict__ Crow = &g_C[(size_t)b * 100 * 512];

    __shared__ __align__(16) float Q1sh[NNODE * 128];
    for (int f = tid; f < 3200; f += 256) {
        const int n = f >> 5, c4 = f & 31;
        *(float4*)&Q1sh[n * 128 + c4 * 4] =
            *(const float4*)&Crow[(size_t)n * 512 + 384 + c4 * 4];
    }
    __syncthreads();

    float4 kr[4][4];
    int nn[4];
#pragma unroll
    for (int j = 0; j < 4; j++) {
        nn[j] = l32 + 32 * j;
#pragma unroll
        for (int i = 0; i < 4; i++) {
            kr[j][i] = (nn[j] < 100)
                ? *(const float4*)&Crow[(size_t)nn[j] * 512 + h * 16 + i * 4]
                : make_float4(0.f, 0.f, 0.f, 0.f);
        }
    }
    float4 qc[4], qp[4];
#pragma unroll
    for (int i = 0; i < 4; i++) {
        qc[i] = *(const float4*)&g_qcap[h * 16 + i * 4];
        qp[i] = *(const float4*)&g_qpool[(size_t)b * 128 + h * 16 + i * 4];
    }
    float sp[4];
#pragma unroll
    for (int j = 0; j < 4; j++) {
        float dc = 0.f, dp = 0.f;
#pragma unroll
        for (int i = 0; i < 4; i++) {
            dc = fmaf(kr[j][i].x, qc[i].x, dc); dc = fmaf(kr[j][i].y, qc[i].y, dc);
            dc = fmaf(kr[j][i].z, qc[i].z, dc); dc = fmaf(kr[j][i].w, qc[i].w, dc);
            dp = fmaf(kr[j][i].x, qp[i].x, dp); dp = fmaf(kr[j][i].y, qp[i].y, dp);
            dp = fmaf(kr[j][i].z, qp[i].z, dp); dp = fmaf(kr[j][i].w, qp[i].w, dp);
        }
        sp[j] = dp;
        if (nn[j] < 100)
            g_Scap[(size_t)b * 800 + h * 100 + nn[j]] = dc * 0.25f;
    }

    float* __restrict__ S1b = &g_S1[(size_t)b * 80000];
    for (int m = 0; m < 100; m++) {
        float4 q[4];
#pragma unroll
        for (int i = 0; i < 4; i++)
            q[i] = *(float4*)&Q1sh[m * 128 + h * 16 + i * 4];
#pragma unroll
        for (int j = 0; j < 4; j++) {
            if (nn[j] < 100) {
                float d = 0.f;
#pragma unroll
                for (int i = 0; i < 4; i++) {
                    d = fmaf(kr[j][i].x, q[i].x, d); d = fmaf(kr[j][i].y, q[i].y, d);
                    d = fmaf(kr[j][i].z, q[i].z, d); d = fmaf(kr[j][i].w, q[i].w, d);
                }
                S1b[(size_t)m * 800 + h * 100 + nn[j]] = (d + sp[j]) * 0.25f;
            }
        }
    }
}

// ---------------- kernel 3: sequential decode, 1 barrier/step ----------------
__global__ __launch_bounds__(256) void decode_kernel(
    const float* __restrict__ capacity, const float* __restrict__ demand,
    const int* __restrict__ nsteps_p, const int* __restrict__ T_p,
    float* __restrict__ out)
{
    __shared__ float u_buf[2 * 800];    // [parity][r<8][n<100]
    __shared__ int   act_sh[512];

    const int tid = threadIdx.x;
    const int b   = blockIdx.x;
    const int nsteps = nsteps_p[0];
    const float invT = 1.0f / (float)T_p[0];
    const float base_cap = capacity[0];
    const float inv_sqrt_h = 0.08838834764831845f;  // 1/sqrt(128)

    const float4* __restrict__ C4  = (const float4*)&g_C[(size_t)b * 100 * 512];
    const float*  __restrict__ S1b = &g_S1[(size_t)b * 80000];

    const int w = tid >> 6, l = tid & 63;
    const int g = l >> 3, f = l & 7;
    const int F = 8 * w + f;                 // global float4 col 0..31
    const int h8 = tid >> 5, l32 = tid & 31; // B mapping: head h8, nodes l32+32j

    // ---- persistent registers
    float4 Vreg[13], K2r[13];
#pragma unroll
    for (int m = 0; m < 13; m++) {
        const int n = g + 8 * m;
        const bool v = n < 100;
        Vreg[m] = v ? C4[(size_t)n * 128 + 32 + F] : make_float4(0.f, 0.f, 0.f, 0.f);
        K2r[m]  = v ? C4[(size_t)n * 128 + 64 + F] : make_float4(0.f, 0.f, 0.f, 0.f);
    }
    float s1r[4], scapr[4], d4[4];
#pragma unroll
    for (int j = 0; j < 4; j++) {
        const int nj = l32 + 32 * j;
        const bool v = nj < 100;
        scapr[j] = v ? g_Scap[(size_t)b * 800 + h8 * 100 + nj] : 0.f;
        s1r[j]   = v ? S1b[h8 * 100 + nj] : 0.f;
        d4[j]    = v ? demand[b * 100 + nj] : 1.0e30f;
    }
    const float de0 = demand[b * 100 + l];
    const float de1 = (l + 64 < 100) ? demand[b * 100 + l + 64] : 1.0e30f;
    bool me0 = false, me1 = false;      // mask1 for nodes l, l+64
    unsigned mb4 = 0;                   // mask1 bits for B's 4 nodes
    float cap_r = capacity[b];
    float depot_r;
    {
        const bool am0 = (l == 0) ? true : (de0 > cap_r);
        const bool am1 = (l + 64 >= 100) ? true : (de1 > cap_r);
        depot_r = __all(am0 && am1) ? 0.f : 1.f;
    }
    float logp_r = 0.f;
    int visited_r = 0;
    int ub = 0;

    for (int s = 0; s < nsteps; s++) {
        const float cap = cap_r;

        // ---- B: scores + per-head softmax, normalized attn in a[]
        float a[4];
        {
            float sc[4];
#pragma unroll
            for (int j = 0; j < 4; j++) {
                const int nj = l32 + 32 * j;
                const bool m = (nj == 0) ? (depot_r != 0.f)
                    : (((mb4 >> j) & 1u) || (d4[j] > cap));
                const float raw = fmaf(cap, scapr[j], s1r[j]);
                sc[j] = (nj < 100 && !m) ? raw : NEGV;
            }
            float mx = fmaxf(fmaxf(sc[0], sc[1]), fmaxf(sc[2], sc[3]));
            for (int off = 16; off; off >>= 1)
                mx = fmaxf(mx, __shfl_xor(mx, off, 32));
            float tot = 0.f;
#pragma unroll
            for (int j = 0; j < 4; j++) { a[j] = fast_exp(sc[j] - mx); tot += a[j]; }
            for (int off = 16; off; off >>= 1) tot += __shfl_xor(tot, off, 32);
            const float rt = fast_rcp(tot);
#pragma unroll
            for (int j = 0; j < 4; j++) a[j] *= rt;
        }

        // ---- C: glimpse cols 4F..4F+3 (attn via intra-wave shfl)
        float4 gp4 = make_float4(0.f, 0.f, 0.f, 0.f);
#pragma unroll
        for (int m = 0; m < 13; m++) {
            const int src = ((f >> 2) << 5) | (8 * (m & 3) + g);
            const float av = __shfl(a[m >> 2], src, 64);
            gp4.x = fmaf(av, Vreg[m].x, gp4.x);
            gp4.y = fmaf(av, Vreg[m].y, gp4.y);
            gp4.z = fmaf(av, Vreg[m].z, gp4.z);
            gp4.w = fmaf(av, Vreg[m].w, gp4.w);
        }
#pragma unroll
        for (int off = 8; off <= 32; off <<= 1) {
            gp4.x += __shfl_xor(gp4.x, off, 64);
            gp4.y += __shfl_xor(gp4.y, off, 64);
            gp4.z += __shfl_xor(gp4.z, off, 64);
            gp4.w += __shfl_xor(gp4.w, off, 64);
        }

        // ---- U: u-partials over this wave's 32 cols -> u_buf rows 2w,2w+1
        {
            float pm[13];
#pragma unroll
            for (int m = 0; m < 13; m++) {
                float p = gp4.x * K2r[m].x;
                p = fmaf(gp4.y, K2r[m].y, p);
                p = fmaf(gp4.z, K2r[m].z, p);
                p = fmaf(gp4.w, K2r[m].w, p);
                pm[m] = p;
            }
#pragma unroll
            for (int m = 0; m < 13; m++) pm[m] += __shfl_xor(pm[m], 1, 64);
#pragma unroll
            for (int m = 0; m < 13; m++) pm[m] += __shfl_xor(pm[m], 2, 64);
            if ((f & 3) == 0) {
                const int r = w * 2 + (f >> 2);
#pragma unroll
                for (int m = 0; m < 13; m++) {
                    const int n = g + 8 * m;
                    if (n < 100) u_buf[ub + r * 100 + n] = pm[m];
                }
            }
        }
        __syncthreads();

        // ---- E: redundant per-wave argmax + lse + state update
        float v0, v1 = -3.0e38f;
        {
            float s8 = 0.f;
#pragma unroll
            for (int r = 0; r < 8; r++) s8 += u_buf[ub + r * 100 + l];
            const float u0 = tanh10(s8 * inv_sqrt_h);
            const bool m0 = (l == 0) ? (depot_r != 0.f) : (me0 || de0 > cap);
            v0 = (m0 ? NEGV : u0) * invT;
            if (l + 64 < 100) {
                float t8 = 0.f;
#pragma unroll
                for (int r = 0; r < 8; r++) t8 += u_buf[ub + r * 100 + l + 64];
                const float u1 = tanh10(t8 * inv_sqrt_h);
                const bool m1 = (me1 || de1 > cap);
                v1 = (m1 ? NEGV : u1) * invT;
            }
        }
        float bv; int bi;
        if (v1 > v0) { bv = v1; bi = l + 64; } else { bv = v0; bi = l; }
#pragma unroll
        for (int off = 1; off < 64; off <<= 1) {
            const float ov = __shfl_xor(bv, off, 64);
            const int   oi = __shfl_xor(bi, off, 64);
            if (ov > bv || (ov == bv && oi < bi)) { bv = ov; bi = oi; }
        }
        const int idx = bi;

        // prefetch next S1 row ASAP (overlaps rest of E)
#pragma unroll
        for (int j = 0; j < 4; j++) {
            const int nj = l32 + 32 * j;
            if (nj < 100)
                s1r[j] = S1b[(size_t)idx * 800 + h8 * 100 + nj];
        }

        float tt = fast_exp(v0 - bv) + ((l + 64 < 100) ? fast_exp(v1 - bv) : 0.f);
#pragma unroll
        for (int off = 1; off < 64; off <<= 1) tt += __shfl_xor(tt, off, 64);

        const float d_sel = (idx >= 64) ? de1 : de0;
        const float dmd_idx = __shfl(d_sel, idx & 63, 64);
        const float capn = (idx == 0) ? base_cap : (cap - dmd_idx);

        if (visited_r < 99) logp_r += -__logf(tt);
        visited_r += (idx > 0) ? 1 : 0;
        me0 = me0 || (l == idx && idx > 0);
        me1 = me1 || (l + 64 == idx);
#pragma unroll
        for (int j = 0; j < 4; j++)
            if ((l32 + 32 * j) == idx && idx > 0) mb4 |= (1u << j);

        const bool am0 = (l == 0) ? true : (me0 || de0 > capn);
        const bool am1 = (l + 64 >= 100) ? true : (me1 || de1 > capn);
        const bool allc = __all(am0 && am1);
        depot_r = allc ? 0.f : ((idx == 0) ? 1.f : 0.f);
        cap_r = capn;
        if (tid == 0) act_sh[s] = idx;
        ub ^= 800;
    }

    __syncthreads();
    for (int t = tid; t < nsteps; t += 256)
        out[(size_t)b * nsteps + t] = (float)act_sh[t];
    if (tid == 0)
        out[(size_t)gridDim.x * nsteps + b] = logp_r;
}

// ---------------- launcher ---------------------------------------------------
extern "C" void kernel_launch(void* const* d_in, const int* in_sizes, int n_in,
                              void* d_out, int out_size, void* d_ws, size_t ws_size,
                              hipStream_t stream) {
    const float* enc    = (const float*)d_in[0];
    const float* pool   = (const float*)d_in[1];
    const float* cap    = (const float*)d_in[2];
    const float* demand = (const float*)d_in[3];
    const float* fc_w   = (const float*)d_in[4];
    const float* fc1_w  = (const float*)d_in[5];
    const float* Wq     = (const float*)d_in[6];
    const float* Wk     = (const float*)d_in[7];
    const float* Wv     = (const float*)d_in[8];
    const float* Wo     = (const float*)d_in[9];
    const float* Wk2    = (const float*)d_in[10];
    const int*   nst    = (const int*)d_in[11];
    const int*   Tp     = (const int*)d_in[12];
    float* out = (float*)d_out;

    prep_kernel<<<641, 128, 0, stream>>>(Wk, Wv, Wk2, Wo, Wq, fc_w, fc1_w);
    gemm_kernel<<<dim3(800, 4), 256, 0, stream>>>(enc, 0);
    gemm_kernel<<<dim3(8, 1),   256, 0, stream>>>(pool, 1);
    s1_kernel<<<1024, 256, 0, stream>>>();
    decode_kernel<<<1024, 256, 0, stream>>>(cap, demand, nst, Tp, out);
}